// Round 10
// baseline (595.742 us; speedup 1.0000x reference)
//
#include <hip/hip_runtime.h>
#include <hip/hip_cooperative_groups.h>

namespace cg = cooperative_groups;

// Problem constants
#define TD 128        // D
#define TS 1024       // SIZE
#define TT 2048       // T
#define NROWS 32768   // B*T
#define EMA_W 0.99f

// d_out layout (flat fp32): [quantized BxDxT][diff][new_embedding SxD][new_usage S]
#define OFF_Q     0
#define OFF_DIFF  4194304
#define OFF_EMB   4194305
#define OFF_USAGE 4325377

// ws layout (words). End = 4,656,196 w = 18.62 MB < 19.15 MB (R7-proven bound)
#define WS_COUNTS  0         // 1024 f
#define WS_CODES   1024      // 32768 i (byte 4096, 16-aligned for int4)
#define WS_ROWLIST 33792     // 32768 i
#define WS_OFFS    66560     // 1025 i
#define WS_CURSOR  67585     // 1024 i
#define WS_DIFFACC 68609     // 64 f
#define WS_BESTV   68676     // 4*32768 f
#define WS_BESTI   199748    // 4*32768 i
#define WS_PART    330820    // 131072 f
#define WS_XHI     461892    // 4194304 f16 = 2097152 w (byte 1847568 %16==0)
#define WS_XLO     2559044   // 2097152 w (byte 10236176 %16==0) -> end 4656196

typedef _Float16 f16x8 __attribute__((ext_vector_type(8)));
typedef float    f32x4 __attribute__((ext_vector_type(4)));

// ================= K1: fused dist (A-convert + B LDS-stage + e2 + argmin) ==============
// grid 1024; decode: range = bid&255 (row-tile), split = bid>>8 (code quarter).
// Same-range splits are congruent mod 8 -> same XCD -> x A-slices L2-shared.
__launch_bounds__(256, 2)
__global__ void vq_dist_k(const float* __restrict__ x, const float* __restrict__ emb,
                          float* __restrict__ wsV, int* __restrict__ wsI,
                          _Float16* __restrict__ xhi, _Float16* __restrict__ xlo,
                          float* __restrict__ counts, float* __restrict__ part,
                          float* __restrict__ diffacc) {
    __shared__ __align__(16) _Float16 bhl[64 * 128];   // 16 KB hi panel
    __shared__ __align__(16) _Float16 bll[64 * 128];   // 16 KB lo panel
    __shared__ float e2s[256];

    const int tid  = threadIdx.x;
    const int lane = tid & 63, wid = tid >> 6;
    const int l15  = lane & 15, lk = lane >> 4;
    const int rangeidx = blockIdx.x & 255;
    const int split    = blockIdx.x >> 8;
    const int n0   = rangeidx * 128;
    const int cbase = split * 256;
    const int b = n0 >> 11, t0 = n0 & (TT - 1);
    const int nrow = n0 + wid * 32;

    // zero duties for the tail kernel (visible after kernel boundary)
    if (split == 1) {
        float* p = part + rangeidx * 512;
        p[tid] = 0.f; p[tid + 256] = 0.f;
    } else if (split == 2) {
        if (rangeidx < 4) counts[rangeidx * 256 + tid] = 0.f;
        if (rangeidx == 4 && tid < 64) diffacc[tid] = 0.f;
    }

    // ---- A fragments from x (fp32 -> f16 hi/lo); verified map: row=lane&15, k=(lane>>4)*8+j
    f16x8 ahi[2][4], alo[2][4];
    #pragma unroll
    for (int fr = 0; fr < 2; fr++) {
        const int rt = t0 + wid * 32 + fr * 16 + l15;
        #pragma unroll
        for (int ks = 0; ks < 4; ks++) {
            float av[8];
            #pragma unroll
            for (int j = 0; j < 8; j++)
                av[j] = x[(size_t)(b * TD + ks * 32 + lk * 8 + j) * TT + rt];
            #pragma unroll
            for (int j = 0; j < 8; j++) {
                _Float16 h = (_Float16)av[j];
                ahi[fr][ks][j] = h;
                alo[fr][ks][j] = (_Float16)(av[j] - (float)h);
            }
        }
    }
    // split-0 blocks persist xhi/xlo [N][D] for the tail's gather-sum
    if (split == 0) {
        #pragma unroll
        for (int fr = 0; fr < 2; fr++) {
            const size_t rowbase = (size_t)(nrow + fr * 16 + l15) * TD;
            #pragma unroll
            for (int ks = 0; ks < 4; ks++) {
                *(f16x8*)(xhi + rowbase + ks * 32 + lk * 8) = ahi[fr][ks];
                *(f16x8*)(xlo + rowbase + ks * 32 + lk * 8) = alo[fr][ks];
            }
        }
    }

    // ---- e2 for this block's 256 codes (fp32, matches reference) ----
    {
        const float4* er = (const float4*)(emb + (size_t)(cbase + tid) * TD);
        float s = 0.f;
        #pragma unroll
        for (int i = 0; i < 32; i++) {
            float4 v = er[i];
            s = fmaf(v.x, v.x, s); s = fmaf(v.y, v.y, s);
            s = fmaf(v.z, v.z, s); s = fmaf(v.w, v.w, s);
        }
        e2s[tid] = s;   // visible after first __syncthreads below
    }

    float bestV[8]; int bestI[8];
    #pragma unroll
    for (int i = 0; i < 8; i++) { bestV[i] = 3.4e38f; bestI[i] = 0; }

    const int srow = tid >> 2, sq = tid & 3;
    const int skey = (srow & 7) << 4;        // write-side XOR swizzle
    const int rkey = (l15 & 7) << 4;         // read-side (row%8 == l15%8)

    for (int tl = 0; tl < 4; ++tl) {
        const int c0 = cbase + tl * 64;
        // stage 64-code B panel from fp32 emb, hi/lo split on the fly, swizzled
        {
            const float4* src = (const float4*)(emb + (size_t)(c0 + srow) * TD) + sq * 8;
            char* ph = (char*)bhl + srow * 256;
            char* pl = (char*)bll + srow * 256;
            #pragma unroll
            for (int i = 0; i < 4; i++) {
                float4 v0 = src[i * 2], v1 = src[i * 2 + 1];
                float vv[8] = {v0.x, v0.y, v0.z, v0.w, v1.x, v1.y, v1.z, v1.w};
                f16x8 h, l;
                #pragma unroll
                for (int j = 0; j < 8; j++) {
                    _Float16 hh = (_Float16)vv[j];
                    h[j] = hh;
                    l[j] = (_Float16)(vv[j] - (float)hh);
                }
                const int off = (sq * 64 + i * 16) ^ skey;
                *(f16x8*)(ph + off) = h;
                *(f16x8*)(pl + off) = l;
            }
        }
        __syncthreads();

        f32x4 acc[2][4];
        #pragma unroll
        for (int fr = 0; fr < 2; fr++)
            #pragma unroll
            for (int fc = 0; fc < 4; fc++)
                acc[fr][fc] = (f32x4){0.f, 0.f, 0.f, 0.f};

        #pragma unroll
        for (int ks = 0; ks < 4; ks++) {
            #pragma unroll
            for (int fc = 0; fc < 4; fc++) {
                const int row = fc * 16 + l15;
                const int off = row * 256 + ((ks * 64 + lk * 16) ^ rkey);
                f16x8 bh = *(const f16x8*)((const char*)bhl + off);
                f16x8 bl = *(const f16x8*)((const char*)bll + off);
                #pragma unroll
                for (int fr = 0; fr < 2; fr++) {
                    acc[fr][fc] = __builtin_amdgcn_mfma_f32_16x16x32_f16(ahi[fr][ks], bh, acc[fr][fc], 0, 0, 0);
                    acc[fr][fc] = __builtin_amdgcn_mfma_f32_16x16x32_f16(ahi[fr][ks], bl, acc[fr][fc], 0, 0, 0);
                    acc[fr][fc] = __builtin_amdgcn_mfma_f32_16x16x32_f16(alo[fr][ks], bh, acc[fr][fc], 0, 0, 0);
                }
            }
        }

        float e2v[4];
        #pragma unroll
        for (int fc = 0; fc < 4; fc++) e2v[fc] = e2s[tl * 64 + fc * 16 + l15];
        #pragma unroll
        for (int fr = 0; fr < 2; fr++)
            #pragma unroll
            for (int i = 0; i < 4; i++)
                #pragma unroll
                for (int fc = 0; fc < 4; fc++) {
                    float sc = fmaf(-2.f, acc[fr][fc][i], e2v[fc]);
                    const int slot = fr * 4 + i;
                    if (sc < bestV[slot]) { bestV[slot] = sc; bestI[slot] = c0 + fc * 16 + l15; }
                }
        __syncthreads();
    }

    // argmin across the 16 lanes of each lk-group (R9-proven)
    #pragma unroll
    for (int sl = 0; sl < 8; sl++) {
        #pragma unroll
        for (int m = 8; m >= 1; m >>= 1) {
            float ov = __shfl_xor(bestV[sl], m, 64);
            int   oi = __shfl_xor(bestI[sl], m, 64);
            if (ov < bestV[sl] || (ov == bestV[sl] && oi < bestI[sl])) {
                bestV[sl] = ov; bestI[sl] = oi;
            }
        }
    }
    #pragma unroll
    for (int fr = 0; fr < 2; fr++)
        #pragma unroll
        for (int i = 0; i < 4; i++)
            if (l15 == fr * 4 + i) {
                const int r = nrow + fr * 16 + lk * 4 + i;
                wsV[split * NROWS + r] = bestV[fr * 4 + i];
                wsI[split * NROWS + r] = bestI[fr * 4 + i];
            }
}

// ================= tail phase bodies (coop + fallback) =================

__device__ void phase_A(const float* __restrict__ wsV, const int* __restrict__ wsI,
                        int* __restrict__ codes, float* __restrict__ counts,
                        int start, int stride) {
    for (int n = start; n < NROWS; n += stride) {
        float bv = wsV[n]; int bi = wsI[n];
        #pragma unroll
        for (int s = 1; s < 4; s++) {
            float v = wsV[s * NROWS + n];
            if (v < bv) { bv = v; bi = wsI[s * NROWS + n]; }  // strict <: split order = code order
        }
        codes[n] = bi;
        atomicAdd(&counts[bi], 1.0f);
    }
}

__device__ void phase_scan(const float* __restrict__ counts, const float* __restrict__ usage,
                           int* __restrict__ offs, int* __restrict__ cursor,
                           float* __restrict__ dout, int* ip) {
    const int t = threadIdx.x, lane = t & 63, wid = t >> 6;
    int c4[4];
    #pragma unroll
    for (int j = 0; j < 4; j++) c4[j] = (int)counts[t * 4 + j];
    int s = c4[0] + c4[1] + c4[2] + c4[3];
    int v = s;
    #pragma unroll
    for (int off = 1; off < 64; off <<= 1) {
        int tt = __shfl_up(v, off, 64);
        if (lane >= off) v += tt;
    }
    if (lane == 63) ip[wid] = v;
    __syncthreads();
    int base = 0;
    for (int w = 0; w < wid; w++) base += ip[w];
    int run = base + v - s;
    #pragma unroll
    for (int j = 0; j < 4; j++) {
        int i = t * 4 + j;
        offs[i] = run; cursor[i] = run;
        dout[OFF_USAGE + i] = EMA_W * usage[i] + (1.0f - EMA_W) * counts[i];
        run += c4[j];
    }
    if (t == 255) offs[TS] = run;
}

__device__ void phase_epi(const float* __restrict__ x, const float* __restrict__ emb,
                          const int* __restrict__ codes, float* __restrict__ dout,
                          float* __restrict__ diffacc, int start, int stride) {
    const float4* x4p = (const float4*)x;
    const float4* e4p = (const float4*)emb;
    float4* out4 = (float4*)(dout + OFF_Q);
    float local = 0.f;
    for (int idx = start; idx < 262144; idx += stride) {
        const int row4 = idx >> 9, t4 = idx & 511;
        const int b = row4 >> 5, d0q = row4 & 31;
        const int nb2 = b * TT + t4 * 4;
        const int4 c4 = *(const int4*)(codes + nb2);
        const float4 q0 = e4p[(size_t)c4.x * 32 + d0q];
        const float4 q1 = e4p[(size_t)c4.y * 32 + d0q];
        const float4 q2 = e4p[(size_t)c4.z * 32 + d0q];
        const float4 q3 = e4p[(size_t)c4.w * 32 + d0q];
#define EPI_STEP(J, C0, C1, C2, C3) { \
        size_t plane = ((size_t)b * TD + d0q * 4 + J) * 512 + t4; \
        float4 xv = x4p[plane]; \
        float4 q = make_float4(C0, C1, C2, C3); \
        out4[plane] = q; \
        float dx = xv.x - q.x; local = fmaf(dx, dx, local); \
        dx = xv.y - q.y; local = fmaf(dx, dx, local); \
        dx = xv.z - q.z; local = fmaf(dx, dx, local); \
        dx = xv.w - q.w; local = fmaf(dx, dx, local); }
        EPI_STEP(0, q0.x, q1.x, q2.x, q3.x)
        EPI_STEP(1, q0.y, q1.y, q2.y, q3.y)
        EPI_STEP(2, q0.z, q1.z, q2.z, q3.z)
        EPI_STEP(3, q0.w, q1.w, q2.w, q3.w)
#undef EPI_STEP
    }
    #pragma unroll
    for (int off = 32; off; off >>= 1) local += __shfl_down(local, off, 64);
    if ((threadIdx.x & 63) == 0)
        atomicAdd(&diffacc[(blockIdx.x * 4 + (threadIdx.x >> 6)) & 63], local);
}

__device__ void phase_scatter(const int* __restrict__ codes, int* __restrict__ cursor,
                              int* __restrict__ rowlist, int start, int stride) {
    for (int n = start; n < NROWS; n += stride) {
        int pos = atomicAdd(&cursor[codes[n]], 1);
        rowlist[pos] = n;
    }
}

__device__ void phase_sum2(const _Float16* __restrict__ xhi, const _Float16* __restrict__ xlo,
                           const int* __restrict__ offs, const int* __restrict__ rowlist,
                           float* __restrict__ part, float* red) {
    const int tid = threadIdx.x;
    const int g = tid >> 7, d = tid & 127;
    for (int un = blockIdx.x; un < TS * 4; un += gridDim.x) {
        const int s = un >> 2, sp = un & 3;
        const int beg = offs[s], end = offs[s + 1];
        float a0 = 0.f, a1 = 0.f;
        int i = beg + sp * 2 + g;
        for (; i + 8 < end; i += 16) {
            int n0 = rowlist[i], n1 = rowlist[i + 8];
            a0 += (float)xhi[(size_t)n0 * TD + d] + (float)xlo[(size_t)n0 * TD + d];
            a1 += (float)xhi[(size_t)n1 * TD + d] + (float)xlo[(size_t)n1 * TD + d];
        }
        if (i < end) {
            int n0 = rowlist[i];
            a0 += (float)xhi[(size_t)n0 * TD + d] + (float)xlo[(size_t)n0 * TD + d];
        }
        red[tid] = a0 + a1;
        __syncthreads();
        if (tid < 128) {
            float p = red[tid] + red[tid + 128];
            if (p != 0.f) atomicAdd(&part[(size_t)s * TD + tid], p);
        }
        __syncthreads();
    }
}

__device__ void phase_fin(const float* __restrict__ emb, const float* __restrict__ counts,
                          const float* __restrict__ part, const float* __restrict__ diffacc,
                          float* __restrict__ dout, int start, int stride) {
    for (int g = start; g < TS * TD; g += stride) {
        int s = g >> 7;
        float cnt = counts[s];
        float e = emb[g];
        float sum = part[g];
        float tgt = (cnt > 0.f) ? (sum / cnt) : e;
        dout[OFF_EMB + g] = EMA_W * e + (1.0f - EMA_W) * tgt;
    }
    if (blockIdx.x == 0 && threadIdx.x < 64) {
        float v = diffacc[threadIdx.x];
        #pragma unroll
        for (int off = 32; off; off >>= 1) v += __shfl_down(v, off, 64);
        if (threadIdx.x == 0)
            dout[OFF_DIFF] = v * (1.0f / ((float)NROWS * (float)TD));
    }
}

// ================= K2: cooperative tail =================
__launch_bounds__(256)
__global__ void vq_tail_k(const float* wsV, const int* wsI, int* codes, float* counts,
                          const float* x, const float* emb, const float* usage,
                          float* dout, float* diffacc, int* offs, int* cursor,
                          int* rowlist, const _Float16* xhi, const _Float16* xlo,
                          float* part) {
    cg::grid_group grid = cg::this_grid();
    __shared__ __align__(16) float red[256];
    __shared__ int ip[4];
    const int G = gridDim.x;
    phase_A(wsV, wsI, codes, counts, blockIdx.x * 256 + threadIdx.x, G * 256);
    grid.sync();
    if (blockIdx.x == 0)
        phase_scan(counts, usage, offs, cursor, dout, ip);
    else
        phase_epi(x, emb, codes, dout, diffacc,
                  (blockIdx.x - 1) * 256 + threadIdx.x, (G - 1) * 256);
    grid.sync();
    phase_scatter(codes, cursor, rowlist, blockIdx.x * 256 + threadIdx.x, G * 256);
    grid.sync();
    phase_sum2(xhi, xlo, offs, rowlist, part, red);
    grid.sync();
    phase_fin(emb, counts, part, diffacc, dout, blockIdx.x * 256 + threadIdx.x, G * 256);
}

// ================= fallback standalone kernels =================
__global__ void vq_A_f(const float* wsV, const int* wsI, int* codes, float* counts) {
    phase_A(wsV, wsI, codes, counts, blockIdx.x * 256 + threadIdx.x, gridDim.x * 256);
}
__global__ void vq_scan_f(const float* counts, const float* usage, int* offs, int* cursor,
                          float* dout) {
    __shared__ int ip[4];
    phase_scan(counts, usage, offs, cursor, dout, ip);
}
__global__ void vq_epi_f(const float* x, const float* emb, const int* codes, float* dout,
                         float* diffacc) {
    phase_epi(x, emb, codes, dout, diffacc, blockIdx.x * 256 + threadIdx.x, gridDim.x * 256);
}
__global__ void vq_scatter_f(const int* codes, int* cursor, int* rowlist) {
    phase_scatter(codes, cursor, rowlist, blockIdx.x * 256 + threadIdx.x, gridDim.x * 256);
}
__global__ void vq_sum2_f(const _Float16* xhi, const _Float16* xlo, const int* offs,
                          const int* rowlist, float* part) {
    __shared__ __align__(16) float red[256];
    phase_sum2(xhi, xlo, offs, rowlist, part, red);
}
__global__ void vq_fin_f(const float* emb, const float* counts, const float* part,
                         const float* diffacc, float* dout) {
    phase_fin(emb, counts, part, diffacc, dout, blockIdx.x * 256 + threadIdx.x, gridDim.x * 256);
}

extern "C" void kernel_launch(void* const* d_in, const int* in_sizes, int n_in,
                              void* d_out, int out_size, void* d_ws, size_t ws_size,
                              hipStream_t stream) {
    const float* x     = (const float*)d_in[0];
    const float* emb   = (const float*)d_in[1];
    const float* usage = (const float*)d_in[2];
    float* dout = (float*)d_out;

    float* wsf = (float*)d_ws;
    int*   wsi = (int*)d_ws;
    float* counts  = wsf + WS_COUNTS;
    int*   codes   = wsi + WS_CODES;
    int*   rowlist = wsi + WS_ROWLIST;
    int*   offs    = wsi + WS_OFFS;
    int*   cursor  = wsi + WS_CURSOR;
    float* diffacc = wsf + WS_DIFFACC;
    float* wsV     = wsf + WS_BESTV;
    int*   wsI     = wsi + WS_BESTI;
    float* part    = wsf + WS_PART;
    _Float16* xhi  = (_Float16*)(wsf + WS_XHI);
    _Float16* xlo  = (_Float16*)(wsf + WS_XLO);

    vq_dist_k<<<1024, 256, 0, stream>>>(x, emb, wsV, wsI, xhi, xlo, counts, part, diffacc);

    int nb = 0;
    hipError_t oerr = hipOccupancyMaxActiveBlocksPerMultiprocessor(&nb, vq_tail_k, 256, 0);
    if (oerr != hipSuccess || nb < 1) nb = 1;
    if (nb > 8) nb = 8;
    int G = nb * 256;
    if (G > 2048) G = 2048;

    const _Float16* cxhi = xhi; const _Float16* cxlo = xlo;
    const float* cwsV = wsV; const int* cwsI = wsI;
    void* args[] = { (void*)&cwsV, (void*)&cwsI, (void*)&codes, (void*)&counts,
                     (void*)&x, (void*)&emb, (void*)&usage, (void*)&dout,
                     (void*)&diffacc, (void*)&offs, (void*)&cursor, (void*)&rowlist,
                     (void*)&cxhi, (void*)&cxlo, (void*)&part };
    hipError_t lerr = hipLaunchCooperativeKernel(vq_tail_k, dim3(G), dim3(256), args, 0, stream);
    if (lerr != hipSuccess) {
        vq_A_f<<<128, 256, 0, stream>>>(wsV, wsI, codes, counts);
        vq_scan_f<<<1, 256, 0, stream>>>(counts, usage, offs, cursor, dout);
        vq_epi_f<<<1024, 256, 0, stream>>>(x, emb, codes, dout, diffacc);
        vq_scatter_f<<<128, 256, 0, stream>>>(codes, cursor, rowlist);
        vq_sum2_f<<<4096, 256, 0, stream>>>(xhi, xlo, offs, rowlist, part);
        vq_fin_f<<<512, 256, 0, stream>>>(emb, counts, part, diffacc, dout);
    }
}

// Round 11
// 167.194 us; speedup vs baseline: 3.5632x; 3.5632x over previous
//
#include <hip/hip_runtime.h>

// Problem constants
#define TD 128        // D
#define TS 1024       // SIZE
#define TT 2048       // T
#define NROWS 32768   // B*T
#define EMA_W 0.99f

// d_out layout (flat fp32): [quantized BxDxT][diff][new_embedding SxD][new_usage S]
#define OFF_Q     0
#define OFF_DIFF  4194304
#define OFF_EMB   4194305
#define OFF_USAGE 4325377

// ws layout (words). End = 4,656,196 w = 18.62 MB < 19.15 MB (R7-proven bound)
#define WS_COUNTS  0         // 1024 f
#define WS_CODES   1024      // 32768 i (byte 4096, 16-aligned)
#define WS_ROWLIST 33792     // 32768 i
#define WS_OFFS    66560     // 1025 i
#define WS_CURSOR  67585     // 1024 i
#define WS_DIFFACC 68609     // 64 f
#define WS_BESTV   68676     // 4*32768 f
#define WS_BESTI   199748    // 4*32768 i
#define WS_XHI     461892    // 4194304 f16 = 2097152 w (byte 1847568 %16==0)
#define WS_XLO     2559044   // 2097152 w -> end 4656196

typedef _Float16 f16x8 __attribute__((ext_vector_type(8)));
typedef float    f32x4 __attribute__((ext_vector_type(4)));

// ================= K1: fused dist (R10-verified body) ==============
// grid 1024; range = bid&255 (row-tile), split = bid>>8 (code quarter).
// Same-range splits congruent mod 8 -> same XCD -> x A-slices L2-shared.
__launch_bounds__(256, 2)
__global__ void vq_dist_k(const float* __restrict__ x, const float* __restrict__ emb,
                          float* __restrict__ wsV, int* __restrict__ wsI,
                          _Float16* __restrict__ xhi, _Float16* __restrict__ xlo,
                          float* __restrict__ counts, float* __restrict__ diffacc) {
    __shared__ __align__(16) _Float16 bhl[64 * 128];   // 16 KB hi panel
    __shared__ __align__(16) _Float16 bll[64 * 128];   // 16 KB lo panel
    __shared__ float e2s[256];

    const int tid  = threadIdx.x;
    const int lane = tid & 63, wid = tid >> 6;
    const int l15  = lane & 15, lk = lane >> 4;
    const int rangeidx = blockIdx.x & 255;
    const int split    = blockIdx.x >> 8;
    const int n0   = rangeidx * 128;
    const int cbase = split * 256;
    const int b = n0 >> 11, t0 = n0 & (TT - 1);
    const int nrow = n0 + wid * 32;

    // zero duties for downstream kernels
    if (split == 2) {
        if (rangeidx < 4) counts[rangeidx * 256 + tid] = 0.f;
        if (rangeidx == 4 && tid < 64) diffacc[tid] = 0.f;
    }

    // ---- A fragments from x (fp32 -> f16 hi/lo); verified map: row=lane&15, k=(lane>>4)*8+j
    f16x8 ahi[2][4], alo[2][4];
    #pragma unroll
    for (int fr = 0; fr < 2; fr++) {
        const int rt = t0 + wid * 32 + fr * 16 + l15;
        #pragma unroll
        for (int ks = 0; ks < 4; ks++) {
            float av[8];
            #pragma unroll
            for (int j = 0; j < 8; j++)
                av[j] = x[(size_t)(b * TD + ks * 32 + lk * 8 + j) * TT + rt];
            #pragma unroll
            for (int j = 0; j < 8; j++) {
                _Float16 h = (_Float16)av[j];
                ahi[fr][ks][j] = h;
                alo[fr][ks][j] = (_Float16)(av[j] - (float)h);
            }
        }
    }
    // split-0 blocks persist xhi/xlo [N][D] for the tail's gather-sum
    if (split == 0) {
        #pragma unroll
        for (int fr = 0; fr < 2; fr++) {
            const size_t rowbase = (size_t)(nrow + fr * 16 + l15) * TD;
            #pragma unroll
            for (int ks = 0; ks < 4; ks++) {
                *(f16x8*)(xhi + rowbase + ks * 32 + lk * 8) = ahi[fr][ks];
                *(f16x8*)(xlo + rowbase + ks * 32 + lk * 8) = alo[fr][ks];
            }
        }
    }

    // ---- e2 for this block's 256 codes (fp32) ----
    {
        const float4* er = (const float4*)(emb + (size_t)(cbase + tid) * TD);
        float s = 0.f;
        #pragma unroll
        for (int i = 0; i < 32; i++) {
            float4 v = er[i];
            s = fmaf(v.x, v.x, s); s = fmaf(v.y, v.y, s);
            s = fmaf(v.z, v.z, s); s = fmaf(v.w, v.w, s);
        }
        e2s[tid] = s;   // visible after first __syncthreads
    }

    float bestV[8]; int bestI[8];
    #pragma unroll
    for (int i = 0; i < 8; i++) { bestV[i] = 3.4e38f; bestI[i] = 0; }

    const int srow = tid >> 2, sq = tid & 3;
    const int skey = (srow & 7) << 4;        // write-side XOR swizzle
    const int rkey = (l15 & 7) << 4;         // read-side (row%8 == l15%8)

    for (int tl = 0; tl < 4; ++tl) {
        const int c0 = cbase + tl * 64;
        // stage 64-code B panel from fp32 emb, hi/lo split on the fly, swizzled
        {
            const float4* src = (const float4*)(emb + (size_t)(c0 + srow) * TD) + sq * 8;
            char* ph = (char*)bhl + srow * 256;
            char* pl = (char*)bll + srow * 256;
            #pragma unroll
            for (int i = 0; i < 4; i++) {
                float4 v0 = src[i * 2], v1 = src[i * 2 + 1];
                float vv[8] = {v0.x, v0.y, v0.z, v0.w, v1.x, v1.y, v1.z, v1.w};
                f16x8 h, l;
                #pragma unroll
                for (int j = 0; j < 8; j++) {
                    _Float16 hh = (_Float16)vv[j];
                    h[j] = hh;
                    l[j] = (_Float16)(vv[j] - (float)hh);
                }
                const int off = (sq * 64 + i * 16) ^ skey;
                *(f16x8*)(ph + off) = h;
                *(f16x8*)(pl + off) = l;
            }
        }
        __syncthreads();

        f32x4 acc[2][4];
        #pragma unroll
        for (int fr = 0; fr < 2; fr++)
            #pragma unroll
            for (int fc = 0; fc < 4; fc++)
                acc[fr][fc] = (f32x4){0.f, 0.f, 0.f, 0.f};

        #pragma unroll
        for (int ks = 0; ks < 4; ks++) {
            #pragma unroll
            for (int fc = 0; fc < 4; fc++) {
                const int row = fc * 16 + l15;
                const int off = row * 256 + ((ks * 64 + lk * 16) ^ rkey);
                f16x8 bh = *(const f16x8*)((const char*)bhl + off);
                f16x8 bl = *(const f16x8*)((const char*)bll + off);
                #pragma unroll
                for (int fr = 0; fr < 2; fr++) {
                    acc[fr][fc] = __builtin_amdgcn_mfma_f32_16x16x32_f16(ahi[fr][ks], bh, acc[fr][fc], 0, 0, 0);
                    acc[fr][fc] = __builtin_amdgcn_mfma_f32_16x16x32_f16(ahi[fr][ks], bl, acc[fr][fc], 0, 0, 0);
                    acc[fr][fc] = __builtin_amdgcn_mfma_f32_16x16x32_f16(alo[fr][ks], bh, acc[fr][fc], 0, 0, 0);
                }
            }
        }

        float e2v[4];
        #pragma unroll
        for (int fc = 0; fc < 4; fc++) e2v[fc] = e2s[tl * 64 + fc * 16 + l15];
        #pragma unroll
        for (int fr = 0; fr < 2; fr++)
            #pragma unroll
            for (int i = 0; i < 4; i++)
                #pragma unroll
                for (int fc = 0; fc < 4; fc++) {
                    float sc = fmaf(-2.f, acc[fr][fc][i], e2v[fc]);
                    const int slot = fr * 4 + i;
                    if (sc < bestV[slot]) { bestV[slot] = sc; bestI[slot] = c0 + fc * 16 + l15; }
                }
        __syncthreads();
    }

    // argmin across the 16 lanes of each lk-group
    #pragma unroll
    for (int sl = 0; sl < 8; sl++) {
        #pragma unroll
        for (int m = 8; m >= 1; m >>= 1) {
            float ov = __shfl_xor(bestV[sl], m, 64);
            int   oi = __shfl_xor(bestI[sl], m, 64);
            if (ov < bestV[sl] || (ov == bestV[sl] && oi < bestI[sl])) {
                bestV[sl] = ov; bestI[sl] = oi;
            }
        }
    }
    #pragma unroll
    for (int fr = 0; fr < 2; fr++)
        #pragma unroll
        for (int i = 0; i < 4; i++)
            if (l15 == fr * 4 + i) {
                const int r = nrow + fr * 16 + lk * 4 + i;
                wsV[split * NROWS + r] = bestV[fr * 4 + i];
                wsI[split * NROWS + r] = bestI[fr * 4 + i];
            }
}

// ================= K2: merge + codes + counts + quantized + diff =================
__global__ void vq_epi_k(const float* __restrict__ x, const float* __restrict__ emb,
                         const float* __restrict__ wsV, const int* __restrict__ wsI,
                         int* __restrict__ codes, float* __restrict__ counts,
                         float* __restrict__ dout, float* __restrict__ diffacc) {
    const int idx  = blockIdx.x * 256 + threadIdx.x;  // 0..262143
    const int row4 = idx >> 9;
    const int t4   = idx & 511;
    const int b    = row4 >> 5;
    const int d0q  = row4 & 31;
    const int nb   = b * TT + t4 * 4;
    int c[4];
    #pragma unroll
    for (int j = 0; j < 4; j++) {
        float bv = wsV[nb + j]; int bi = wsI[nb + j];
        #pragma unroll
        for (int s = 1; s < 4; s++) {
            float v = wsV[s * NROWS + nb + j];
            if (v < bv) { bv = v; bi = wsI[s * NROWS + nb + j]; }  // strict <: split order = code order
        }
        c[j] = bi;
    }
    if (d0q == 0) {
        *(int4*)(codes + nb) = make_int4(c[0], c[1], c[2], c[3]);
        #pragma unroll
        for (int j = 0; j < 4; j++) atomicAdd(&counts[c[j]], 1.0f);
    }
    const float4* x4p = (const float4*)x;
    const float4* e4p = (const float4*)emb;
    float4* out4 = (float4*)(dout + OFF_Q);
    const float4 q0 = e4p[(size_t)c[0] * 32 + d0q];
    const float4 q1 = e4p[(size_t)c[1] * 32 + d0q];
    const float4 q2 = e4p[(size_t)c[2] * 32 + d0q];
    const float4 q3 = e4p[(size_t)c[3] * 32 + d0q];
    float local = 0.f;
#define EPI_STEP(J, C0, C1, C2, C3) { \
        size_t plane = ((size_t)b * TD + d0q * 4 + J) * 512 + t4; \
        float4 xv = x4p[plane]; \
        float4 q = make_float4(C0, C1, C2, C3); \
        out4[plane] = q; \
        float dx = xv.x - q.x; local = fmaf(dx, dx, local); \
        dx = xv.y - q.y; local = fmaf(dx, dx, local); \
        dx = xv.z - q.z; local = fmaf(dx, dx, local); \
        dx = xv.w - q.w; local = fmaf(dx, dx, local); }
    EPI_STEP(0, q0.x, q1.x, q2.x, q3.x)
    EPI_STEP(1, q0.y, q1.y, q2.y, q3.y)
    EPI_STEP(2, q0.z, q1.z, q2.z, q3.z)
    EPI_STEP(3, q0.w, q1.w, q2.w, q3.w)
#undef EPI_STEP
    #pragma unroll
    for (int off = 32; off; off >>= 1) local += __shfl_down(local, off, 64);
    if ((threadIdx.x & 63) == 0)
        atomicAdd(&diffacc[(blockIdx.x * 4 + (threadIdx.x >> 6)) & 63], local);
}

// ================= K3: scan counts -> offs/cursor; usage EMA (1 block) =================
__global__ void vq_scan_k(const float* __restrict__ counts, const float* __restrict__ usage,
                          int* __restrict__ offs, int* __restrict__ cursor,
                          float* __restrict__ dout) {
    __shared__ int ip[4];
    const int t = threadIdx.x, lane = t & 63, wid = t >> 6;
    int c4[4];
    #pragma unroll
    for (int j = 0; j < 4; j++) c4[j] = (int)counts[t * 4 + j];
    int s = c4[0] + c4[1] + c4[2] + c4[3];
    int v = s;
    #pragma unroll
    for (int off = 1; off < 64; off <<= 1) {
        int tt = __shfl_up(v, off, 64);
        if (lane >= off) v += tt;
    }
    if (lane == 63) ip[wid] = v;
    __syncthreads();
    int base = 0;
    for (int w = 0; w < wid; w++) base += ip[w];
    int run = base + v - s;
    #pragma unroll
    for (int j = 0; j < 4; j++) {
        int i = t * 4 + j;
        offs[i] = run; cursor[i] = run;
        dout[OFF_USAGE + i] = EMA_W * usage[i] + (1.0f - EMA_W) * counts[i];
        run += c4[j];
    }
    if (t == 255) offs[TS] = run;
}

// ================= K4: scatter row indices =================
__global__ void vq_scatter_k(const int* __restrict__ codes, int* __restrict__ cursor,
                             int* __restrict__ rowlist) {
    int n = blockIdx.x * 256 + threadIdx.x;
    int pos = atomicAdd(&cursor[codes[n]], 1);
    rowlist[pos] = n;
}

// ================= K5: gather-sum + EMA write (one 1024-thr block per code) ============
__launch_bounds__(1024)
__global__ void vq_sumfin_k(const _Float16* __restrict__ xhi, const _Float16* __restrict__ xlo,
                            const float* __restrict__ emb,
                            const int* __restrict__ offs, const int* __restrict__ rowlist,
                            const float* __restrict__ diffacc, float* __restrict__ dout) {
    __shared__ float red[1024];
    const int s = blockIdx.x;
    const int tid = threadIdx.x;
    const int g = tid >> 7, d = tid & 127;     // 8 row-groups x 128 dims
    const int beg = offs[s], end = offs[s + 1];

    float a0 = 0.f, a1 = 0.f;
    int i = beg + g;
    for (; i + 8 < end; i += 16) {
        int n0 = rowlist[i], n1 = rowlist[i + 8];
        a0 += (float)xhi[(size_t)n0 * TD + d] + (float)xlo[(size_t)n0 * TD + d];
        a1 += (float)xhi[(size_t)n1 * TD + d] + (float)xlo[(size_t)n1 * TD + d];
    }
    if (i < end) {
        int n0 = rowlist[i];
        a0 += (float)xhi[(size_t)n0 * TD + d] + (float)xlo[(size_t)n0 * TD + d];
    }
    red[tid] = a0 + a1;
    __syncthreads();
    if (tid < 512) red[tid] += red[tid + 512];
    __syncthreads();
    if (tid < 256) red[tid] += red[tid + 256];
    __syncthreads();
    if (tid < 128) {
        float sum = red[tid] + red[tid + 128];
        int cnt = end - beg;
        float e = emb[(size_t)s * TD + tid];
        float tgt = (cnt > 0) ? (sum / (float)cnt) : e;
        dout[OFF_EMB + (size_t)s * TD + tid] = EMA_W * e + (1.0f - EMA_W) * tgt;
    }
    if (s == 0 && tid < 64) {
        float v = diffacc[tid];
        #pragma unroll
        for (int off = 32; off; off >>= 1) v += __shfl_down(v, off, 64);
        if (tid == 0)
            dout[OFF_DIFF] = v * (1.0f / ((float)NROWS * (float)TD));
    }
}

extern "C" void kernel_launch(void* const* d_in, const int* in_sizes, int n_in,
                              void* d_out, int out_size, void* d_ws, size_t ws_size,
                              hipStream_t stream) {
    const float* x     = (const float*)d_in[0];
    const float* emb   = (const float*)d_in[1];
    const float* usage = (const float*)d_in[2];
    float* dout = (float*)d_out;

    float* wsf = (float*)d_ws;
    int*   wsi = (int*)d_ws;
    float* counts  = wsf + WS_COUNTS;
    int*   codes   = wsi + WS_CODES;
    int*   rowlist = wsi + WS_ROWLIST;
    int*   offs    = wsi + WS_OFFS;
    int*   cursor  = wsi + WS_CURSOR;
    float* diffacc = wsf + WS_DIFFACC;
    float* wsV     = wsf + WS_BESTV;
    int*   wsI     = wsi + WS_BESTI;
    _Float16* xhi  = (_Float16*)(wsf + WS_XHI);
    _Float16* xlo  = (_Float16*)(wsf + WS_XLO);

    vq_dist_k<<<1024, 256, 0, stream>>>(x, emb, wsV, wsI, xhi, xlo, counts, diffacc);
    vq_epi_k<<<1024, 256, 0, stream>>>(x, emb, wsV, wsI, codes, counts, dout, diffacc);
    vq_scan_k<<<1, 256, 0, stream>>>(counts, usage, offs, cursor, dout);
    vq_scatter_k<<<NROWS / 256, 256, 0, stream>>>(codes, cursor, rowlist);
    vq_sumfin_k<<<TS, 1024, 0, stream>>>(xhi, xlo, emb, offs, rowlist, diffacc, dout);
}

// Round 12
// 149.770 us; speedup vs baseline: 3.9777x; 1.1163x over previous
//
#include <hip/hip_runtime.h>

// Problem constants
#define TD 128        // D
#define TS 1024       // SIZE
#define TT 2048       // T
#define NROWS 32768   // B*T
#define EMA_W 0.99f

// d_out layout (flat fp32): [quantized BxDxT][diff][new_embedding SxD][new_usage S]
#define OFF_Q     0
#define OFF_DIFF  4194304
#define OFF_EMB   4194305
#define OFF_USAGE 4325377

// ws layout (words). End = 4,489,280 w = 17.96 MB < 19.15 MB (R7-proven bound)
#define WS_CODES   0         // 32768 i (byte 0, int4-aligned)
#define WS_DIFFACC 32768     // 64 f
#define WS_BESTV   32832     // 4*32768 f
#define WS_BESTI   163904    // 4*32768 i
#define WS_XHI     294976    // 4194304 f16 = 2097152 w (byte 1179904 %16==0)
#define WS_XLO     2392128   // 2097152 w (byte 9568512 %16==0) -> end 4489280

typedef _Float16 f16x8 __attribute__((ext_vector_type(8)));
typedef float    f32x4 __attribute__((ext_vector_type(4)));

// ================= K1: fused dist (R10/R11-verified body; e2 folded into staging) =======
// grid 1024; range = bid&255 (row-tile), split = bid>>8 (code quarter).
__launch_bounds__(256, 2)
__global__ void vq_dist_k(const float* __restrict__ x, const float* __restrict__ emb,
                          float* __restrict__ wsV, int* __restrict__ wsI,
                          _Float16* __restrict__ xhi, _Float16* __restrict__ xlo,
                          float* __restrict__ diffacc) {
    __shared__ __align__(16) _Float16 bhl[64 * 128];   // 16 KB hi panel
    __shared__ __align__(16) _Float16 bll[64 * 128];   // 16 KB lo panel
    __shared__ float e2sv[64];

    const int tid  = threadIdx.x;
    const int lane = tid & 63, wid = tid >> 6;
    const int l15  = lane & 15, lk = lane >> 4;
    const int rangeidx = blockIdx.x & 255;
    const int split    = blockIdx.x >> 8;
    const int n0   = rangeidx * 128;
    const int cbase = split * 256;
    const int b = n0 >> 11, t0 = n0 & (TT - 1);
    const int nrow = n0 + wid * 32;

    // zero duty for epi's diff accumulator
    if (split == 2 && rangeidx == 4 && tid < 64) diffacc[tid] = 0.f;

    // ---- A fragments from x (fp32 -> f16 hi/lo); verified map: row=lane&15, k=(lane>>4)*8+j
    f16x8 ahi[2][4], alo[2][4];
    #pragma unroll
    for (int fr = 0; fr < 2; fr++) {
        const int rt = t0 + wid * 32 + fr * 16 + l15;
        #pragma unroll
        for (int ks = 0; ks < 4; ks++) {
            float av[8];
            #pragma unroll
            for (int j = 0; j < 8; j++)
                av[j] = x[(size_t)(b * TD + ks * 32 + lk * 8 + j) * TT + rt];
            #pragma unroll
            for (int j = 0; j < 8; j++) {
                _Float16 h = (_Float16)av[j];
                ahi[fr][ks][j] = h;
                alo[fr][ks][j] = (_Float16)(av[j] - (float)h);
            }
        }
    }
    // split-0 blocks persist xhi/xlo [N][D] for the tail's gather-sum
    if (split == 0) {
        #pragma unroll
        for (int fr = 0; fr < 2; fr++) {
            const size_t rowbase = (size_t)(nrow + fr * 16 + l15) * TD;
            #pragma unroll
            for (int ks = 0; ks < 4; ks++) {
                *(f16x8*)(xhi + rowbase + ks * 32 + lk * 8) = ahi[fr][ks];
                *(f16x8*)(xlo + rowbase + ks * 32 + lk * 8) = alo[fr][ks];
            }
        }
    }

    float bestV[8]; int bestI[8];
    #pragma unroll
    for (int i = 0; i < 8; i++) { bestV[i] = 3.4e38f; bestI[i] = 0; }

    const int srow = tid >> 2, sq = tid & 3;
    const int skey = (srow & 7) << 4;        // write-side XOR swizzle
    const int rkey = (l15 & 7) << 4;         // read-side (row%8 == l15%8)

    for (int tl = 0; tl < 4; ++tl) {
        const int c0 = cbase + tl * 64;
        // stage 64-code B panel from fp32 emb, hi/lo split + e2 partial on the fly
        {
            const float4* src = (const float4*)(emb + (size_t)(c0 + srow) * TD) + sq * 8;
            char* ph = (char*)bhl + srow * 256;
            char* pl = (char*)bll + srow * 256;
            float sqs = 0.f;
            #pragma unroll
            for (int i = 0; i < 4; i++) {
                float4 v0 = src[i * 2], v1 = src[i * 2 + 1];
                float vv[8] = {v0.x, v0.y, v0.z, v0.w, v1.x, v1.y, v1.z, v1.w};
                f16x8 h, l;
                #pragma unroll
                for (int j = 0; j < 8; j++) {
                    _Float16 hh = (_Float16)vv[j];
                    h[j] = hh;
                    l[j] = (_Float16)(vv[j] - (float)hh);
                    sqs = fmaf(vv[j], vv[j], sqs);
                }
                const int off = (sq * 64 + i * 16) ^ skey;
                *(f16x8*)(ph + off) = h;
                *(f16x8*)(pl + off) = l;
            }
            // reduce e2 across the 4 sq-lanes (consecutive lanes of the wave)
            sqs += __shfl_xor(sqs, 1, 64);
            sqs += __shfl_xor(sqs, 2, 64);
            if (sq == 0) e2sv[srow] = sqs;
        }
        __syncthreads();

        f32x4 acc[2][4];
        #pragma unroll
        for (int fr = 0; fr < 2; fr++)
            #pragma unroll
            for (int fc = 0; fc < 4; fc++)
                acc[fr][fc] = (f32x4){0.f, 0.f, 0.f, 0.f};

        #pragma unroll
        for (int ks = 0; ks < 4; ks++) {
            #pragma unroll
            for (int fc = 0; fc < 4; fc++) {
                const int row = fc * 16 + l15;
                const int off = row * 256 + ((ks * 64 + lk * 16) ^ rkey);
                f16x8 bh = *(const f16x8*)((const char*)bhl + off);
                f16x8 bl = *(const f16x8*)((const char*)bll + off);
                #pragma unroll
                for (int fr = 0; fr < 2; fr++) {
                    acc[fr][fc] = __builtin_amdgcn_mfma_f32_16x16x32_f16(ahi[fr][ks], bh, acc[fr][fc], 0, 0, 0);
                    acc[fr][fc] = __builtin_amdgcn_mfma_f32_16x16x32_f16(ahi[fr][ks], bl, acc[fr][fc], 0, 0, 0);
                    acc[fr][fc] = __builtin_amdgcn_mfma_f32_16x16x32_f16(alo[fr][ks], bh, acc[fr][fc], 0, 0, 0);
                }
            }
        }

        float e2v[4];
        #pragma unroll
        for (int fc = 0; fc < 4; fc++) e2v[fc] = e2sv[fc * 16 + l15];
        #pragma unroll
        for (int fr = 0; fr < 2; fr++)
            #pragma unroll
            for (int i = 0; i < 4; i++)
                #pragma unroll
                for (int fc = 0; fc < 4; fc++) {
                    float sc = fmaf(-2.f, acc[fr][fc][i], e2v[fc]);
                    const int slot = fr * 4 + i;
                    if (sc < bestV[slot]) { bestV[slot] = sc; bestI[slot] = c0 + fc * 16 + l15; }
                }
        __syncthreads();
    }

    // argmin across the 16 lanes of each lk-group
    #pragma unroll
    for (int sl = 0; sl < 8; sl++) {
        #pragma unroll
        for (int m = 8; m >= 1; m >>= 1) {
            float ov = __shfl_xor(bestV[sl], m, 64);
            int   oi = __shfl_xor(bestI[sl], m, 64);
            if (ov < bestV[sl] || (ov == bestV[sl] && oi < bestI[sl])) {
                bestV[sl] = ov; bestI[sl] = oi;
            }
        }
    }
    #pragma unroll
    for (int fr = 0; fr < 2; fr++)
        #pragma unroll
        for (int i = 0; i < 4; i++)
            if (l15 == fr * 4 + i) {
                const int r = nrow + fr * 16 + lk * 4 + i;
                wsV[split * NROWS + r] = bestV[fr * 4 + i];
                wsI[split * NROWS + r] = bestI[fr * 4 + i];
            }
}

// ================= K2: merge + codes + quantized + diff =================
__global__ void vq_epi_k(const float* __restrict__ x, const float* __restrict__ emb,
                         const float* __restrict__ wsV, const int* __restrict__ wsI,
                         int* __restrict__ codes, float* __restrict__ dout,
                         float* __restrict__ diffacc) {
    const int idx  = blockIdx.x * 256 + threadIdx.x;  // 0..262143
    const int row4 = idx >> 9;
    const int t4   = idx & 511;
    const int b    = row4 >> 5;
    const int d0q  = row4 & 31;
    const int nb   = b * TT + t4 * 4;
    int c[4];
    #pragma unroll
    for (int j = 0; j < 4; j++) {
        float bv = wsV[nb + j]; int bi = wsI[nb + j];
        #pragma unroll
        for (int s = 1; s < 4; s++) {
            float v = wsV[s * NROWS + nb + j];
            if (v < bv) { bv = v; bi = wsI[s * NROWS + nb + j]; }  // strict <: split order = code order
        }
        c[j] = bi;
    }
    if (d0q == 0)
        *(int4*)(codes + nb) = make_int4(c[0], c[1], c[2], c[3]);
    const float4* x4p = (const float4*)x;
    const float4* e4p = (const float4*)emb;
    float4* out4 = (float4*)(dout + OFF_Q);
    const float4 q0 = e4p[(size_t)c[0] * 32 + d0q];
    const float4 q1 = e4p[(size_t)c[1] * 32 + d0q];
    const float4 q2 = e4p[(size_t)c[2] * 32 + d0q];
    const float4 q3 = e4p[(size_t)c[3] * 32 + d0q];
    float local = 0.f;
#define EPI_STEP(J, C0, C1, C2, C3) { \
        size_t plane = ((size_t)b * TD + d0q * 4 + J) * 512 + t4; \
        float4 xv = x4p[plane]; \
        float4 q = make_float4(C0, C1, C2, C3); \
        out4[plane] = q; \
        float dx = xv.x - q.x; local = fmaf(dx, dx, local); \
        dx = xv.y - q.y; local = fmaf(dx, dx, local); \
        dx = xv.z - q.z; local = fmaf(dx, dx, local); \
        dx = xv.w - q.w; local = fmaf(dx, dx, local); }
    EPI_STEP(0, q0.x, q1.x, q2.x, q3.x)
    EPI_STEP(1, q0.y, q1.y, q2.y, q3.y)
    EPI_STEP(2, q0.z, q1.z, q2.z, q3.z)
    EPI_STEP(3, q0.w, q1.w, q2.w, q3.w)
#undef EPI_STEP
    #pragma unroll
    for (int off = 32; off; off >>= 1) local += __shfl_down(local, off, 64);
    if ((threadIdx.x & 63) == 0)
        atomicAdd(&diffacc[(blockIdx.x * 4 + (threadIdx.x >> 6)) & 63], local);
}

// ================= K3: per-code scan-gather + EMA + usage + diff =================
// one block per code; scans codes[] in 4 chunks into an LDS hit-list, gathers rows.
__launch_bounds__(512)
__global__ void vq_sumfin_k(const _Float16* __restrict__ xhi, const _Float16* __restrict__ xlo,
                            const float* __restrict__ emb, const float* __restrict__ usage,
                            const int* __restrict__ codes, const float* __restrict__ diffacc,
                            float* __restrict__ dout) {
    __shared__ int list[8192];
    __shared__ int lcnt;
    __shared__ float red[512];
    const int s = blockIdx.x;
    const int tid = threadIdx.x;
    const int g = tid >> 7, d = tid & 127;     // 4 row-groups x 128 dims

    float a0 = 0.f, a1 = 0.f;
    int total = 0;
    for (int ch = 0; ch < 4; ch++) {
        if (tid == 0) lcnt = 0;
        __syncthreads();
        // scan 8192 codes: 512 threads x 4 int4 (coalesced)
        const int4* c4 = (const int4*)(codes + ch * 8192);
        #pragma unroll
        for (int i = 0; i < 4; i++) {
            const int idx = i * 512 + tid;
            const int4 v = c4[idx];
            const int nbase = ch * 8192 + idx * 4;
            if (v.x == s) list[atomicAdd(&lcnt, 1)] = nbase;
            if (v.y == s) list[atomicAdd(&lcnt, 1)] = nbase + 1;
            if (v.z == s) list[atomicAdd(&lcnt, 1)] = nbase + 2;
            if (v.w == s) list[atomicAdd(&lcnt, 1)] = nbase + 3;
        }
        __syncthreads();
        const int cnt = lcnt;
        total += cnt;
        // gather: 4 row-groups, 2-deep unroll (8 rows in flight)
        int i = g;
        for (; i + 4 < cnt; i += 8) {
            const int m0 = list[i], m1 = list[i + 4];
            a0 += (float)xhi[(size_t)m0 * TD + d] + (float)xlo[(size_t)m0 * TD + d];
            a1 += (float)xhi[(size_t)m1 * TD + d] + (float)xlo[(size_t)m1 * TD + d];
        }
        if (i < cnt) {
            const int m0 = list[i];
            a0 += (float)xhi[(size_t)m0 * TD + d] + (float)xlo[(size_t)m0 * TD + d];
        }
        __syncthreads();   // protect list/lcnt reuse next chunk
    }
    red[tid] = a0 + a1;
    __syncthreads();
    if (tid < 128) {
        const float sum = red[tid] + red[tid + 128] + red[tid + 256] + red[tid + 384];
        const float e = emb[(size_t)s * TD + tid];
        const float tgt = (total > 0) ? (sum / (float)total) : e;
        dout[OFF_EMB + (size_t)s * TD + tid] = EMA_W * e + (1.0f - EMA_W) * tgt;
    }
    if (tid == 0)
        dout[OFF_USAGE + s] = EMA_W * usage[s] + (1.0f - EMA_W) * (float)total;
    if (s == 0 && tid >= 256 && tid < 320) {
        float v = diffacc[tid - 256];
        #pragma unroll
        for (int off = 32; off; off >>= 1) v += __shfl_down(v, off, 64);
        if (tid == 256)
            dout[OFF_DIFF] = v * (1.0f / ((float)NROWS * (float)TD));
    }
}

extern "C" void kernel_launch(void* const* d_in, const int* in_sizes, int n_in,
                              void* d_out, int out_size, void* d_ws, size_t ws_size,
                              hipStream_t stream) {
    const float* x     = (const float*)d_in[0];
    const float* emb   = (const float*)d_in[1];
    const float* usage = (const float*)d_in[2];
    float* dout = (float*)d_out;

    float* wsf = (float*)d_ws;
    int*   wsi = (int*)d_ws;
    int*   codes   = wsi + WS_CODES;
    float* diffacc = wsf + WS_DIFFACC;
    float* wsV     = wsf + WS_BESTV;
    int*   wsI     = wsi + WS_BESTI;
    _Float16* xhi  = (_Float16*)(wsf + WS_XHI);
    _Float16* xlo  = (_Float16*)(wsf + WS_XLO);

    vq_dist_k<<<1024, 256, 0, stream>>>(x, emb, wsV, wsI, xhi, xlo, diffacc);
    vq_epi_k<<<1024, 256, 0, stream>>>(x, emb, wsV, wsI, codes, dout, diffacc);
    vq_sumfin_k<<<TS, 512, 0, stream>>>(xhi, xlo, emb, usage, codes, diffacc, dout);
}

// Round 13
// 98.348 us; speedup vs baseline: 6.0575x; 1.5229x over previous
//
#include <hip/hip_runtime.h>

// Problem constants
#define TD 128        // D
#define TS 1024       // SIZE
#define TT 2048       // T
#define NROWS 32768   // B*T
#define EMA_W 0.99f
#define BINCAP 128    // rowbin slots per code (max realistic count ~70)

// d_out layout (flat fp32): [quantized BxDxT][diff][new_embedding SxD][new_usage S]
#define OFF_Q     0
#define OFF_DIFF  4194304
#define OFF_EMB   4194305
#define OFF_USAGE 4325377

// ws layout (words). End = 4,588,608 w = 18.35 MB < 19.15 MB (R7-proven bound)
#define WS_CURSOR  0         // 1024 i
#define WS_ROWBIN  1024      // 131072 i
#define WS_DIFFACC 132096    // 64 f
#define WS_BESTV   132160    // 4*32768 f
#define WS_BESTI   263232    // 4*32768 i
#define WS_XHI     394304    // 4194304 f16 = 2097152 w (byte 1577216 %16==0)
#define WS_XLO     2491456   // 2097152 w (byte 9965824 %16==0) -> end 4588608

typedef _Float16 f16x8 __attribute__((ext_vector_type(8)));
typedef float    f32x4 __attribute__((ext_vector_type(4)));

// ================= K1: fused dist (R10/R11/R12-verified body + T14 B-prefetch) =========
// grid 1024; range = bid&255 (row-tile), split = bid>>8 (code quarter).
__launch_bounds__(256, 2)
__global__ void vq_dist_k(const float* __restrict__ x, const float* __restrict__ emb,
                          float* __restrict__ wsV, int* __restrict__ wsI,
                          _Float16* __restrict__ xhi, _Float16* __restrict__ xlo,
                          int* __restrict__ cursor, float* __restrict__ diffacc) {
    __shared__ __align__(16) _Float16 bhl[64 * 128];   // 16 KB hi panel
    __shared__ __align__(16) _Float16 bll[64 * 128];   // 16 KB lo panel
    __shared__ float e2sv[64];

    const int tid  = threadIdx.x;
    const int lane = tid & 63, wid = tid >> 6;
    const int l15  = lane & 15, lk = lane >> 4;
    const int rangeidx = blockIdx.x & 255;
    const int split    = blockIdx.x >> 8;
    const int n0   = rangeidx * 128;
    const int cbase = split * 256;
    const int b = n0 >> 11, t0 = n0 & (TT - 1);
    const int nrow = n0 + wid * 32;

    // zero duties for epi (cursor + diffacc)
    if (split == 2) {
        if (rangeidx < 4) cursor[rangeidx * 256 + tid] = 0;
        if (rangeidx == 4 && tid < 64) diffacc[tid] = 0.f;
    }

    // ---- A fragments from x (fp32 -> f16 hi/lo); verified map: row=lane&15, k=(lane>>4)*8+j
    f16x8 ahi[2][4], alo[2][4];
    #pragma unroll
    for (int fr = 0; fr < 2; fr++) {
        const int rt = t0 + wid * 32 + fr * 16 + l15;
        #pragma unroll
        for (int ks = 0; ks < 4; ks++) {
            float av[8];
            #pragma unroll
            for (int j = 0; j < 8; j++)
                av[j] = x[(size_t)(b * TD + ks * 32 + lk * 8 + j) * TT + rt];
            #pragma unroll
            for (int j = 0; j < 8; j++) {
                _Float16 h = (_Float16)av[j];
                ahi[fr][ks][j] = h;
                alo[fr][ks][j] = (_Float16)(av[j] - (float)h);
            }
        }
    }
    // split-0 blocks persist xhi/xlo [N][D] for the tail's gather-sum
    if (split == 0) {
        #pragma unroll
        for (int fr = 0; fr < 2; fr++) {
            const size_t rowbase = (size_t)(nrow + fr * 16 + l15) * TD;
            #pragma unroll
            for (int ks = 0; ks < 4; ks++) {
                *(f16x8*)(xhi + rowbase + ks * 32 + lk * 8) = ahi[fr][ks];
                *(f16x8*)(xlo + rowbase + ks * 32 + lk * 8) = alo[fr][ks];
            }
        }
    }

    float bestV[8]; int bestI[8];
    #pragma unroll
    for (int i = 0; i < 8; i++) { bestV[i] = 3.4e38f; bestI[i] = 0; }

    const int srow = tid >> 2, sq = tid & 3;
    const int skey = (srow & 7) << 4;        // write-side XOR swizzle
    const int rkey = (l15 & 7) << 4;         // read-side (row%8 == l15%8)

    // T14: prefetch regs for the B panel (issued during previous tile's MFMA)
    float4 pv[8];
    {
        const float4* src = (const float4*)(emb + (size_t)(cbase + srow) * TD) + sq * 8;
        #pragma unroll
        for (int i = 0; i < 8; i++) pv[i] = src[i];
    }

    for (int tl = 0; tl < 4; ++tl) {
        // convert prefetched fp32 -> f16 hi/lo, write swizzled LDS, fold e2 partial
        {
            char* ph = (char*)bhl + srow * 256;
            char* pl = (char*)bll + srow * 256;
            float sqs = 0.f;
            #pragma unroll
            for (int i = 0; i < 4; i++) {
                float4 v0 = pv[i * 2], v1 = pv[i * 2 + 1];
                float vv[8] = {v0.x, v0.y, v0.z, v0.w, v1.x, v1.y, v1.z, v1.w};
                f16x8 h, l;
                #pragma unroll
                for (int j = 0; j < 8; j++) {
                    _Float16 hh = (_Float16)vv[j];
                    h[j] = hh;
                    l[j] = (_Float16)(vv[j] - (float)hh);
                    sqs = fmaf(vv[j], vv[j], sqs);
                }
                const int off = (sq * 64 + i * 16) ^ skey;
                *(f16x8*)(ph + off) = h;
                *(f16x8*)(pl + off) = l;
            }
            sqs += __shfl_xor(sqs, 1, 64);
            sqs += __shfl_xor(sqs, 2, 64);
            if (sq == 0) e2sv[srow] = sqs;
        }
        __syncthreads();

        if (tl < 3) {   // issue next tile's global loads; they fly during MFMA below
            const float4* src =
                (const float4*)(emb + (size_t)(cbase + (tl + 1) * 64 + srow) * TD) + sq * 8;
            #pragma unroll
            for (int i = 0; i < 8; i++) pv[i] = src[i];
        }

        const int c0 = cbase + tl * 64;
        f32x4 acc[2][4];
        #pragma unroll
        for (int fr = 0; fr < 2; fr++)
            #pragma unroll
            for (int fc = 0; fc < 4; fc++)
                acc[fr][fc] = (f32x4){0.f, 0.f, 0.f, 0.f};

        #pragma unroll
        for (int ks = 0; ks < 4; ks++) {
            #pragma unroll
            for (int fc = 0; fc < 4; fc++) {
                const int row = fc * 16 + l15;
                const int off = row * 256 + ((ks * 64 + lk * 16) ^ rkey);
                f16x8 bh = *(const f16x8*)((const char*)bhl + off);
                f16x8 bl = *(const f16x8*)((const char*)bll + off);
                #pragma unroll
                for (int fr = 0; fr < 2; fr++) {
                    acc[fr][fc] = __builtin_amdgcn_mfma_f32_16x16x32_f16(ahi[fr][ks], bh, acc[fr][fc], 0, 0, 0);
                    acc[fr][fc] = __builtin_amdgcn_mfma_f32_16x16x32_f16(ahi[fr][ks], bl, acc[fr][fc], 0, 0, 0);
                    acc[fr][fc] = __builtin_amdgcn_mfma_f32_16x16x32_f16(alo[fr][ks], bh, acc[fr][fc], 0, 0, 0);
                }
            }
        }

        float e2v[4];
        #pragma unroll
        for (int fc = 0; fc < 4; fc++) e2v[fc] = e2sv[fc * 16 + l15];
        #pragma unroll
        for (int fr = 0; fr < 2; fr++)
            #pragma unroll
            for (int i = 0; i < 4; i++)
                #pragma unroll
                for (int fc = 0; fc < 4; fc++) {
                    float sc = fmaf(-2.f, acc[fr][fc][i], e2v[fc]);
                    const int slot = fr * 4 + i;
                    if (sc < bestV[slot]) { bestV[slot] = sc; bestI[slot] = c0 + fc * 16 + l15; }
                }
        __syncthreads();
    }

    // argmin across the 16 lanes of each lk-group
    #pragma unroll
    for (int sl = 0; sl < 8; sl++) {
        #pragma unroll
        for (int m = 8; m >= 1; m >>= 1) {
            float ov = __shfl_xor(bestV[sl], m, 64);
            int   oi = __shfl_xor(bestI[sl], m, 64);
            if (ov < bestV[sl] || (ov == bestV[sl] && oi < bestI[sl])) {
                bestV[sl] = ov; bestI[sl] = oi;
            }
        }
    }
    #pragma unroll
    for (int fr = 0; fr < 2; fr++)
        #pragma unroll
        for (int i = 0; i < 4; i++)
            if (l15 == fr * 4 + i) {
                const int r = nrow + fr * 16 + lk * 4 + i;
                wsV[split * NROWS + r] = bestV[fr * 4 + i];
                wsI[split * NROWS + r] = bestI[fr * 4 + i];
            }
}

// ================= K2: merge + rowbin-build + quantized + diff =================
__global__ void vq_epi_k(const float* __restrict__ x, const float* __restrict__ emb,
                         const float* __restrict__ wsV, const int* __restrict__ wsI,
                         int* __restrict__ cursor, int* __restrict__ rowbin,
                         float* __restrict__ dout, float* __restrict__ diffacc) {
    const int idx  = blockIdx.x * 256 + threadIdx.x;  // 0..262143
    const int row4 = idx >> 9;
    const int t4   = idx & 511;
    const int b    = row4 >> 5;
    const int d0q  = row4 & 31;
    const int nb   = b * TT + t4 * 4;
    int c[4];
    #pragma unroll
    for (int j = 0; j < 4; j++) {
        float bv = wsV[nb + j]; int bi = wsI[nb + j];
        #pragma unroll
        for (int s = 1; s < 4; s++) {
            float v = wsV[s * NROWS + nb + j];
            if (v < bv) { bv = v; bi = wsI[s * NROWS + nb + j]; }  // strict <: split order = code order
        }
        c[j] = bi;
    }
    if (d0q == 0) {
        #pragma unroll
        for (int j = 0; j < 4; j++) {
            int pos = atomicAdd(&cursor[c[j]], 1);
            if (pos < BINCAP) rowbin[c[j] * BINCAP + pos] = nb + j;
        }
    }
    const float4* x4p = (const float4*)x;
    const float4* e4p = (const float4*)emb;
    float4* out4 = (float4*)(dout + OFF_Q);
    const float4 q0 = e4p[(size_t)c[0] * 32 + d0q];
    const float4 q1 = e4p[(size_t)c[1] * 32 + d0q];
    const float4 q2 = e4p[(size_t)c[2] * 32 + d0q];
    const float4 q3 = e4p[(size_t)c[3] * 32 + d0q];
    float local = 0.f;
#define EPI_STEP(J, C0, C1, C2, C3) { \
        size_t plane = ((size_t)b * TD + d0q * 4 + J) * 512 + t4; \
        float4 xv = x4p[plane]; \
        float4 q = make_float4(C0, C1, C2, C3); \
        out4[plane] = q; \
        float dx = xv.x - q.x; local = fmaf(dx, dx, local); \
        dx = xv.y - q.y; local = fmaf(dx, dx, local); \
        dx = xv.z - q.z; local = fmaf(dx, dx, local); \
        dx = xv.w - q.w; local = fmaf(dx, dx, local); }
    EPI_STEP(0, q0.x, q1.x, q2.x, q3.x)
    EPI_STEP(1, q0.y, q1.y, q2.y, q3.y)
    EPI_STEP(2, q0.z, q1.z, q2.z, q3.z)
    EPI_STEP(3, q0.w, q1.w, q2.w, q3.w)
#undef EPI_STEP
    #pragma unroll
    for (int off = 32; off; off >>= 1) local += __shfl_down(local, off, 64);
    if ((threadIdx.x & 63) == 0)
        atomicAdd(&diffacc[(blockIdx.x * 4 + (threadIdx.x >> 6)) & 63], local);
}

// ================= K3: per-code bin-gather + EMA + usage + diff =================
// one 256-thread block per code: 2 row-groups x 128 dims, 2-deep unroll.
__launch_bounds__(256)
__global__ void vq_sumfin_k(const _Float16* __restrict__ xhi, const _Float16* __restrict__ xlo,
                            const float* __restrict__ emb, const float* __restrict__ usage,
                            const int* __restrict__ cursor, const int* __restrict__ rowbin,
                            const float* __restrict__ diffacc, float* __restrict__ dout) {
    __shared__ float red[256];
    const int s = blockIdx.x;
    const int tid = threadIdx.x;
    const int g = tid >> 7, d = tid & 127;
    const int total = cursor[s];
    const int cnt = (total > BINCAP) ? BINCAP : total;
    const int* bin = rowbin + s * BINCAP;

    float a0 = 0.f, a1 = 0.f;
    int i = g;
    for (; i + 2 < cnt; i += 4) {
        const int m0 = bin[i], m1 = bin[i + 2];
        a0 += (float)xhi[(size_t)m0 * TD + d] + (float)xlo[(size_t)m0 * TD + d];
        a1 += (float)xhi[(size_t)m1 * TD + d] + (float)xlo[(size_t)m1 * TD + d];
    }
    if (i < cnt) {
        const int m0 = bin[i];
        a0 += (float)xhi[(size_t)m0 * TD + d] + (float)xlo[(size_t)m0 * TD + d];
    }
    red[tid] = a0 + a1;
    __syncthreads();
    if (tid < 128) {
        const float sum = red[tid] + red[tid + 128];
        const float e = emb[(size_t)s * TD + tid];
        const float tgt = (total > 0) ? (sum / (float)total) : e;
        dout[OFF_EMB + (size_t)s * TD + tid] = EMA_W * e + (1.0f - EMA_W) * tgt;
    }
    if (tid == 0)
        dout[OFF_USAGE + s] = EMA_W * usage[s] + (1.0f - EMA_W) * (float)total;
    if (s == 0 && tid >= 192) {
        float v = diffacc[tid - 192];
        #pragma unroll
        for (int off = 32; off; off >>= 1) v += __shfl_down(v, off, 64);
        if (tid == 192)
            dout[OFF_DIFF] = v * (1.0f / ((float)NROWS * (float)TD));
    }
}

extern "C" void kernel_launch(void* const* d_in, const int* in_sizes, int n_in,
                              void* d_out, int out_size, void* d_ws, size_t ws_size,
                              hipStream_t stream) {
    const float* x     = (const float*)d_in[0];
    const float* emb   = (const float*)d_in[1];
    const float* usage = (const float*)d_in[2];
    float* dout = (float*)d_out;

    float* wsf = (float*)d_ws;
    int*   wsi = (int*)d_ws;
    int*   cursor  = wsi + WS_CURSOR;
    int*   rowbin  = wsi + WS_ROWBIN;
    float* diffacc = wsf + WS_DIFFACC;
    float* wsV     = wsf + WS_BESTV;
    int*   wsI     = wsi + WS_BESTI;
    _Float16* xhi  = (_Float16*)(wsf + WS_XHI);
    _Float16* xlo  = (_Float16*)(wsf + WS_XLO);

    vq_dist_k<<<1024, 256, 0, stream>>>(x, emb, wsV, wsI, xhi, xlo, cursor, diffacc);
    vq_epi_k<<<1024, 256, 0, stream>>>(x, emb, wsV, wsI, cursor, rowbin, dout, diffacc);
    vq_sumfin_k<<<TS, 256, 0, stream>>>(xhi, xlo, emb, usage, cursor, rowbin, diffacc, dout);
}

// Round 14
// 96.464 us; speedup vs baseline: 6.1758x; 1.0195x over previous
//
#include <hip/hip_runtime.h>

// Problem constants
#define TD 128        // D
#define TS 1024       // SIZE
#define TT 2048       // T
#define NROWS 32768   // B*T
#define EMA_W 0.99f
#define BINCAP 128    // rowbin slots per code (max realistic count ~70)

// d_out layout (flat fp32): [quantized BxDxT][diff][new_embedding SxD][new_usage S]
#define OFF_Q     0
#define OFF_DIFF  4194304
#define OFF_EMB   4194305
#define OFF_USAGE 4325377

// ws layout (words). End = 4,720,704 w = 18.88 MB < 19.15 MB (R7-proven bound)
#define WS_CURSOR  0         // 1024 i
#define WS_ROWBIN  1024      // 131072 i
#define WS_DIFFACC 132096    // 64 f
#define WS_E2      132160    // 1024 f
#define WS_BESTV   133184    // 4*32768 f
#define WS_BESTI   264256    // 4*32768 i
#define WS_EHI     395328    // 131072 f16 = 65536 w (byte 1581312 %16==0)
#define WS_ELO     460864    // 65536 w
#define WS_XHI     526400    // 4194304 f16 = 2097152 w (byte 2105600 %16==0)
#define WS_XLO     2623552   // 2097152 w -> end 4720704

typedef _Float16 f16x8 __attribute__((ext_vector_type(8)));
typedef _Float16 half4 __attribute__((ext_vector_type(4)));
typedef float    f32x4 __attribute__((ext_vector_type(4)));

// ================= K0: prep — x transpose+split, emb split+e2, zeroing ===========
// grid 512 x 256 thr. Bodies verified in R9.
__global__ void vq_prep_k(const float* __restrict__ x, const float* __restrict__ emb,
                          _Float16* __restrict__ xhi, _Float16* __restrict__ xlo,
                          _Float16* __restrict__ ehi, _Float16* __restrict__ elo,
                          float* __restrict__ e2, int* __restrict__ cursor,
                          float* __restrict__ diffacc) {
    __shared__ float xs[64][132];
    const int tid = threadIdx.x, bid = blockIdx.x;
    const int lane = tid & 63, wid = tid >> 6;

    // zero duties
    if (bid < 4) cursor[bid * 256 + tid] = 0;
    if (bid == 4 && tid < 64) diffacc[tid] = 0.f;

    // job B: emb split + e2 (one wave per code row; 2048 waves cover 1024 codes)
    {
        const int s = bid * 4 + wid;
        if (s < TS) {
            size_t base = (size_t)s * TD;
            float v0 = emb[base + lane], v1 = emb[base + 64 + lane];
            _Float16 h0 = (_Float16)v0, h1 = (_Float16)v1;
            ehi[base + lane] = h0;      elo[base + lane] = (_Float16)(v0 - (float)h0);
            ehi[base + 64 + lane] = h1; elo[base + 64 + lane] = (_Float16)(v1 - (float)h1);
            float sq = v0 * v0 + v1 * v1;
            #pragma unroll
            for (int off = 32; off; off >>= 1) sq += __shfl_down(sq, off, 64);
            if (lane == 0) e2[s] = sq;
        }
    }

    // job A: x [B][D][T] -> xhi/xlo [N][D] (LDS transpose + f16 hi/lo split)
    const int b = bid >> 5, tc = bid & 31;
    const float4* x4 = (const float4*)x;
    #pragma unroll
    for (int p = 0; p < 8; p++) {
        int idx = p * 256 + tid;
        int d = idx >> 4, t4 = idx & 15;
        float4 v = x4[((size_t)b * TD + d) * 512 + tc * 16 + t4];
        xs[t4 * 4 + 0][d] = v.x;
        xs[t4 * 4 + 1][d] = v.y;
        xs[t4 * 4 + 2][d] = v.z;
        xs[t4 * 4 + 3][d] = v.w;
    }
    __syncthreads();
    const int ld = tid & 31;
    #pragma unroll
    for (int p = 0; p < 8; p++) {
        int tl = p * 8 + (tid >> 5);
        float4 v = *(const float4*)&xs[tl][ld * 4];
        half4 h, l;
        h[0] = (_Float16)v.x; l[0] = (_Float16)(v.x - (float)h[0]);
        h[1] = (_Float16)v.y; l[1] = (_Float16)(v.y - (float)h[1]);
        h[2] = (_Float16)v.z; l[2] = (_Float16)(v.z - (float)h[2]);
        h[3] = (_Float16)v.w; l[3] = (_Float16)(v.w - (float)h[3]);
        size_t n = (size_t)b * TT + tc * 64 + tl;
        *(half4*)(xhi + n * TD + ld * 4) = h;
        *(half4*)(xlo + n * TD + ld * 4) = l;
    }
}

// ================= K1: dist — pure copy->MFMA (R13 skeleton, conversions removed) ======
// grid 1024; range = bid&255 (row-tile), split = bid>>8 (code quarter).
__launch_bounds__(256, 2)
__global__ void vq_dist_k(const _Float16* __restrict__ xhi, const _Float16* __restrict__ xlo,
                          const _Float16* __restrict__ ehi, const _Float16* __restrict__ elo,
                          const float* __restrict__ e2,
                          float* __restrict__ wsV, int* __restrict__ wsI) {
    __shared__ __align__(16) _Float16 bhl[64 * 128];   // 16 KB hi panel
    __shared__ __align__(16) _Float16 bll[64 * 128];   // 16 KB lo panel
    __shared__ float e2s[256];

    const int tid  = threadIdx.x;
    const int lane = tid & 63, wid = tid >> 6;
    const int l15  = lane & 15, lk = lane >> 4;
    const int rangeidx = blockIdx.x & 255;
    const int split    = blockIdx.x >> 8;
    const int n0   = rangeidx * 128;
    const int cbase = split * 256;
    const int nrow = n0 + wid * 32;

    e2s[tid] = e2[cbase + tid];   // visible after first __syncthreads

    // ---- A fragments from xhi/xlo (verified map: row=lane&15, k=(lane>>4)*8+j)
    f16x8 ahi[2][4], alo[2][4];
    #pragma unroll
    for (int fr = 0; fr < 2; fr++) {
        const size_t rowbase = (size_t)(nrow + fr * 16 + l15) * TD;
        #pragma unroll
        for (int ks = 0; ks < 4; ks++) {
            ahi[fr][ks] = *(const f16x8*)(xhi + rowbase + ks * 32 + lk * 8);
            alo[fr][ks] = *(const f16x8*)(xlo + rowbase + ks * 32 + lk * 8);
        }
    }

    float bestV[8]; int bestI[8];
    #pragma unroll
    for (int i = 0; i < 8; i++) { bestV[i] = 3.4e38f; bestI[i] = 0; }

    const int srow = tid >> 2, sq = tid & 3;
    const int skey = (srow & 7) << 4;        // write-side XOR swizzle
    const int rkey = (l15 & 7) << 4;         // read-side (row%8 == l15%8)

    // T14 prefetch: tile 0's B rows (4 x 16B hi + 4 x 16B lo per thread)
    f16x8 pvh[4], pvl[4];
    {
        const f16x8* sh = (const f16x8*)(ehi + (size_t)(cbase + srow) * TD + sq * 32);
        const f16x8* sl = (const f16x8*)(elo + (size_t)(cbase + srow) * TD + sq * 32);
        #pragma unroll
        for (int i = 0; i < 4; i++) { pvh[i] = sh[i]; pvl[i] = sl[i]; }
    }

    for (int tl = 0; tl < 4; ++tl) {
        // write prefetched panel to swizzled LDS (no conversion)
        {
            char* ph = (char*)bhl + srow * 256;
            char* pl = (char*)bll + srow * 256;
            #pragma unroll
            for (int i = 0; i < 4; i++) {
                const int off = (sq * 64 + i * 16) ^ skey;
                *(f16x8*)(ph + off) = pvh[i];
                *(f16x8*)(pl + off) = pvl[i];
            }
        }
        __syncthreads();

        if (tl < 3) {   // issue next tile's global loads; they fly during MFMA below
            const f16x8* sh =
                (const f16x8*)(ehi + (size_t)(cbase + (tl + 1) * 64 + srow) * TD + sq * 32);
            const f16x8* sl =
                (const f16x8*)(elo + (size_t)(cbase + (tl + 1) * 64 + srow) * TD + sq * 32);
            #pragma unroll
            for (int i = 0; i < 4; i++) { pvh[i] = sh[i]; pvl[i] = sl[i]; }
        }

        const int c0 = cbase + tl * 64;
        f32x4 acc[2][4];
        #pragma unroll
        for (int fr = 0; fr < 2; fr++)
            #pragma unroll
            for (int fc = 0; fc < 4; fc++)
                acc[fr][fc] = (f32x4){0.f, 0.f, 0.f, 0.f};

        #pragma unroll
        for (int ks = 0; ks < 4; ks++) {
            #pragma unroll
            for (int fc = 0; fc < 4; fc++) {
                const int row = fc * 16 + l15;
                const int off = row * 256 + ((ks * 64 + lk * 16) ^ rkey);
                f16x8 bh = *(const f16x8*)((const char*)bhl + off);
                f16x8 bl = *(const f16x8*)((const char*)bll + off);
                #pragma unroll
                for (int fr = 0; fr < 2; fr++) {
                    acc[fr][fc] = __builtin_amdgcn_mfma_f32_16x16x32_f16(ahi[fr][ks], bh, acc[fr][fc], 0, 0, 0);
                    acc[fr][fc] = __builtin_amdgcn_mfma_f32_16x16x32_f16(ahi[fr][ks], bl, acc[fr][fc], 0, 0, 0);
                    acc[fr][fc] = __builtin_amdgcn_mfma_f32_16x16x32_f16(alo[fr][ks], bh, acc[fr][fc], 0, 0, 0);
                }
            }
        }

        float e2v[4];
        #pragma unroll
        for (int fc = 0; fc < 4; fc++) e2v[fc] = e2s[tl * 64 + fc * 16 + l15];
        #pragma unroll
        for (int fr = 0; fr < 2; fr++)
            #pragma unroll
            for (int i = 0; i < 4; i++)
                #pragma unroll
                for (int fc = 0; fc < 4; fc++) {
                    float sc = fmaf(-2.f, acc[fr][fc][i], e2v[fc]);
                    const int slot = fr * 4 + i;
                    if (sc < bestV[slot]) { bestV[slot] = sc; bestI[slot] = c0 + fc * 16 + l15; }
                }
        __syncthreads();
    }

    // argmin across the 16 lanes of each lk-group
    #pragma unroll
    for (int sl = 0; sl < 8; sl++) {
        #pragma unroll
        for (int m = 8; m >= 1; m >>= 1) {
            float ov = __shfl_xor(bestV[sl], m, 64);
            int   oi = __shfl_xor(bestI[sl], m, 64);
            if (ov < bestV[sl] || (ov == bestV[sl] && oi < bestI[sl])) {
                bestV[sl] = ov; bestI[sl] = oi;
            }
        }
    }
    #pragma unroll
    for (int fr = 0; fr < 2; fr++)
        #pragma unroll
        for (int i = 0; i < 4; i++)
            if (l15 == fr * 4 + i) {
                const int r = nrow + fr * 16 + lk * 4 + i;
                wsV[split * NROWS + r] = bestV[fr * 4 + i];
                wsI[split * NROWS + r] = bestI[fr * 4 + i];
            }
}

// ================= K2: merge + rowbin-build + quantized + diff (R13-verified) ==========
__global__ void vq_epi_k(const float* __restrict__ x, const float* __restrict__ emb,
                         const float* __restrict__ wsV, const int* __restrict__ wsI,
                         int* __restrict__ cursor, int* __restrict__ rowbin,
                         float* __restrict__ dout, float* __restrict__ diffacc) {
    const int idx  = blockIdx.x * 256 + threadIdx.x;  // 0..262143
    const int row4 = idx >> 9;
    const int t4   = idx & 511;
    const int b    = row4 >> 5;
    const int d0q  = row4 & 31;
    const int nb   = b * TT + t4 * 4;
    int c[4];
    #pragma unroll
    for (int j = 0; j < 4; j++) {
        float bv = wsV[nb + j]; int bi = wsI[nb + j];
        #pragma unroll
        for (int s = 1; s < 4; s++) {
            float v = wsV[s * NROWS + nb + j];
            if (v < bv) { bv = v; bi = wsI[s * NROWS + nb + j]; }  // strict <: split order = code order
        }
        c[j] = bi;
    }
    if (d0q == 0) {
        #pragma unroll
        for (int j = 0; j < 4; j++) {
            int pos = atomicAdd(&cursor[c[j]], 1);
            if (pos < BINCAP) rowbin[c[j] * BINCAP + pos] = nb + j;
        }
    }
    const float4* x4p = (const float4*)x;
    const float4* e4p = (const float4*)emb;
    float4* out4 = (float4*)(dout + OFF_Q);
    const float4 q0 = e4p[(size_t)c[0] * 32 + d0q];
    const float4 q1 = e4p[(size_t)c[1] * 32 + d0q];
    const float4 q2 = e4p[(size_t)c[2] * 32 + d0q];
    const float4 q3 = e4p[(size_t)c[3] * 32 + d0q];
    float local = 0.f;
#define EPI_STEP(J, C0, C1, C2, C3) { \
        size_t plane = ((size_t)b * TD + d0q * 4 + J) * 512 + t4; \
        float4 xv = x4p[plane]; \
        float4 q = make_float4(C0, C1, C2, C3); \
        out4[plane] = q; \
        float dx = xv.x - q.x; local = fmaf(dx, dx, local); \
        dx = xv.y - q.y; local = fmaf(dx, dx, local); \
        dx = xv.z - q.z; local = fmaf(dx, dx, local); \
        dx = xv.w - q.w; local = fmaf(dx, dx, local); }
    EPI_STEP(0, q0.x, q1.x, q2.x, q3.x)
    EPI_STEP(1, q0.y, q1.y, q2.y, q3.y)
    EPI_STEP(2, q0.z, q1.z, q2.z, q3.z)
    EPI_STEP(3, q0.w, q1.w, q2.w, q3.w)
#undef EPI_STEP
    #pragma unroll
    for (int off = 32; off; off >>= 1) local += __shfl_down(local, off, 64);
    if ((threadIdx.x & 63) == 0)
        atomicAdd(&diffacc[(blockIdx.x * 4 + (threadIdx.x >> 6)) & 63], local);
}

// ================= K3: per-code bin-gather + EMA + usage + diff (R13-verified) =========
__launch_bounds__(256)
__global__ void vq_sumfin_k(const _Float16* __restrict__ xhi, const _Float16* __restrict__ xlo,
                            const float* __restrict__ emb, const float* __restrict__ usage,
                            const int* __restrict__ cursor, const int* __restrict__ rowbin,
                            const float* __restrict__ diffacc, float* __restrict__ dout) {
    __shared__ float red[256];
    const int s = blockIdx.x;
    const int tid = threadIdx.x;
    const int g = tid >> 7, d = tid & 127;
    const int total = cursor[s];
    const int cnt = (total > BINCAP) ? BINCAP : total;
    const int* bin = rowbin + s * BINCAP;

    float a0 = 0.f, a1 = 0.f;
    int i = g;
    for (; i + 2 < cnt; i += 4) {
        const int m0 = bin[i], m1 = bin[i + 2];
        a0 += (float)xhi[(size_t)m0 * TD + d] + (float)xlo[(size_t)m0 * TD + d];
        a1 += (float)xhi[(size_t)m1 * TD + d] + (float)xlo[(size_t)m1 * TD + d];
    }
    if (i < cnt) {
        const int m0 = bin[i];
        a0 += (float)xhi[(size_t)m0 * TD + d] + (float)xlo[(size_t)m0 * TD + d];
    }
    red[tid] = a0 + a1;
    __syncthreads();
    if (tid < 128) {
        const float sum = red[tid] + red[tid + 128];
        const float e = emb[(size_t)s * TD + tid];
        const float tgt = (total > 0) ? (sum / (float)total) : e;
        dout[OFF_EMB + (size_t)s * TD + tid] = EMA_W * e + (1.0f - EMA_W) * tgt;
    }
    if (tid == 0)
        dout[OFF_USAGE + s] = EMA_W * usage[s] + (1.0f - EMA_W) * (float)total;
    if (s == 0 && tid >= 192) {
        float v = diffacc[tid - 192];
        #pragma unroll
        for (int off = 32; off; off >>= 1) v += __shfl_down(v, off, 64);
        if (tid == 192)
            dout[OFF_DIFF] = v * (1.0f / ((float)NROWS * (float)TD));
    }
}

extern "C" void kernel_launch(void* const* d_in, const int* in_sizes, int n_in,
                              void* d_out, int out_size, void* d_ws, size_t ws_size,
                              hipStream_t stream) {
    const float* x     = (const float*)d_in[0];
    const float* emb   = (const float*)d_in[1];
    const float* usage = (const float*)d_in[2];
    float* dout = (float*)d_out;

    float* wsf = (float*)d_ws;
    int*   wsi = (int*)d_ws;
    int*   cursor  = wsi + WS_CURSOR;
    int*   rowbin  = wsi + WS_ROWBIN;
    float* diffacc = wsf + WS_DIFFACC;
    float* e2      = wsf + WS_E2;
    float* wsV     = wsf + WS_BESTV;
    int*   wsI     = wsi + WS_BESTI;
    _Float16* ehi  = (_Float16*)(wsf + WS_EHI);
    _Float16* elo  = (_Float16*)(wsf + WS_ELO);
    _Float16* xhi  = (_Float16*)(wsf + WS_XHI);
    _Float16* xlo  = (_Float16*)(wsf + WS_XLO);

    vq_prep_k<<<512, 256, 0, stream>>>(x, emb, xhi, xlo, ehi, elo, e2, cursor, diffacc);
    vq_dist_k<<<1024, 256, 0, stream>>>(xhi, xlo, ehi, elo, e2, wsV, wsI);
    vq_epi_k<<<1024, 256, 0, stream>>>(x, emb, wsV, wsI, cursor, rowbin, dout, diffacc);
    vq_sumfin_k<<<TS, 256, 0, stream>>>(xhi, xlo, emb, usage, cursor, rowbin, diffacc, dout);
}